// Round 9
// baseline (209.368 us; speedup 1.0000x reference)
//
#include <hip/hip_runtime.h>
#include <math.h>

static constexpr int B_  = 2;
static constexpr int S_  = 2048;
static constexpr int E_  = 1024;
static constexpr int NH_ = 4;
static constexpr int HD_ = 256;
static constexpr int BH_ = B_ * NH_;

typedef __attribute__((ext_vector_type(8))) _Float16 half8;
typedef __attribute__((ext_vector_type(4))) float    f32x4;
typedef __attribute__((ext_vector_type(4))) _Float16 half4v;

// ---------------- Kernel A: gate projections + fp16 convert of Q(/16), K ----------------
__global__ __launch_bounds__(1024) void gates_kernel(
    const float* __restrict__ q, const float* __restrict__ k, const float* __restrict__ v,
    const float* __restrict__ igk, const float* __restrict__ igb,
    const float* __restrict__ fgk, const float* __restrict__ fgb,
    float* __restrict__ ig_out, float* __restrict__ fg_out,
    _Float16* __restrict__ Qh, _Float16* __restrict__ Kh)
{
    __shared__ __align__(16) float4 wi[3 * E_];   // 48 KB
    __shared__ __align__(16) float4 wf[3 * E_];   // 48 KB

    const int t = threadIdx.x;
    #pragma unroll
    for (int i = 0; i < 3; ++i) {
        int e = t + 1024 * i;
        wi[e] = ((const float4*)igk)[e];
        wf[e] = ((const float4*)fgk)[e];
    }
    __syncthreads();

    const int wave = t >> 6;
    const int l    = t & 63;
    const int bs   = blockIdx.x * 16 + wave;     // b*S + s
    const int b = bs >> 11, s = bs & (S_ - 1);
    const float* qrow = q + (size_t)bs * E_;
    const float* krow = k + (size_t)bs * E_;
    const float* vrow = v + (size_t)bs * E_;

    float accI[4] = {0.f,0.f,0.f,0.f}, accF[4] = {0.f,0.f,0.f,0.f};
    #pragma unroll
    for (int j = 0; j < 48; ++j) {
        const int e = l + 64 * j;
        float g;
        if (j < 16)       g = qrow[e];
        else if (j < 32)  g = krow[e - E_];
        else              g = vrow[e - 2 * E_];
        if (j < 16) {
            int hh = e >> 8, d = e & 255;
            Qh[(((size_t)(b * NH_ + hh)) * S_ + s) * HD_ + d] = (_Float16)(g * 0.0625f);
        } else if (j < 32) {
            int e2 = e - E_; int hh = e2 >> 8, d = e2 & 255;
            Kh[(((size_t)(b * NH_ + hh)) * S_ + s) * HD_ + d] = (_Float16)g;
        }
        float4 wiv = wi[e];
        float4 wfv = wf[e];
        accI[0] = fmaf(g, wiv.x, accI[0]); accI[1] = fmaf(g, wiv.y, accI[1]);
        accI[2] = fmaf(g, wiv.z, accI[2]); accI[3] = fmaf(g, wiv.w, accI[3]);
        accF[0] = fmaf(g, wfv.x, accF[0]); accF[1] = fmaf(g, wfv.y, accF[1]);
        accF[2] = fmaf(g, wfv.z, accF[2]); accF[3] = fmaf(g, wfv.w, accF[3]);
    }
    #pragma unroll
    for (int m = 1; m < 64; m <<= 1) {
        #pragma unroll
        for (int h = 0; h < 4; ++h) {
            accI[h] += __shfl_xor(accI[h], m);
            accF[h] += __shfl_xor(accF[h], m);
        }
    }
    if (l == 0) {
        #pragma unroll
        for (int h = 0; h < 4; ++h) {
            ig_out[((size_t)(b * NH_ + h)) * S_ + s] = accI[h] + igb[h];
            fg_out[((size_t)(b * NH_ + h)) * S_ + s] = accF[h] + fgb[h];
        }
    }
}

// ---------------- Kernel B: fused scan (blocks 0..7) + V-transpose (blocks 8..1031) ----------------
__global__ __launch_bounds__(256) void scan_transpose_kernel(
    const float* __restrict__ ig, const float* __restrict__ fg,
    float* __restrict__ AmM, float* __restrict__ G, float* __restrict__ M,
    const float* __restrict__ v, _Float16* __restrict__ Vt)
{
    const int t = threadIdx.x;
    if (blockIdx.x < 8) {
        // ---- log-sigmoid cumsum + cummax scan for head bh ----
        __shared__ float sc[256];
        const int bh = blockIdx.x;
        const float* fgp = fg + (size_t)bh * S_;
        const float* igp = ig + (size_t)bh * S_;
        float ls[8];
        float run = 0.f;
        #pragma unroll
        for (int i = 0; i < 8; ++i) {
            float x = fgp[t * 8 + i];
            float l = (x >= 0.f) ? -log1pf(expf(-x)) : (x - log1pf(expf(x)));
            run += l;
            ls[i] = run;
        }
        sc[t] = run;
        __syncthreads();
        for (int off = 1; off < 256; off <<= 1) {
            float vv = (t >= off) ? sc[t - off] : 0.f;
            __syncthreads();
            sc[t] += vv;
            __syncthreads();
        }
        float excl = sc[t] - run;
        float A[8], g[8], gm[8];
        #pragma unroll
        for (int i = 0; i < 8; ++i) A[i] = excl + ls[i];
        float rmax = -__builtin_inff();
        #pragma unroll
        for (int i = 0; i < 8; ++i) {
            g[i] = igp[t * 8 + i] - A[i];
            rmax = fmaxf(rmax, g[i]);
            gm[i] = rmax;
        }
        __syncthreads();
        sc[t] = rmax;
        __syncthreads();
        for (int off = 1; off < 256; off <<= 1) {
            float vv = (t >= off) ? sc[t - off] : -__builtin_inff();
            __syncthreads();
            sc[t] = fmaxf(sc[t], vv);
            __syncthreads();
        }
        float exm = (t == 0) ? -__builtin_inff() : sc[t - 1];
        #pragma unroll
        for (int i = 0; i < 8; ++i) {
            float cm = fmaxf(exm, gm[i]);
            float Mi = A[i] + cm;
            size_t idx = (size_t)bh * S_ + t * 8 + i;
            AmM[idx] = A[i] - Mi;
            G[idx]   = g[i];
            M[idx]   = Mi;
        }
    } else {
        // ---- V -> fp16 transposed [bh][HD][S], one 64x64 tile ----
        __shared__ float tile[64][65];
        const int m  = blockIdx.x - 8;        // 0..1023
        const int bh = m & 7;
        const int sb = (m >> 3) & 31;
        const int db = m >> 8;                // 0..3
        const int b = bh >> 2, h = bh & 3;
        const int j4 = (t & 15) * 4;
        const int i0 = t >> 4;
        const float* src = v + ((size_t)(b * S_ + sb * 64)) * E_ + h * HD_ + db * 64;
        #pragma unroll
        for (int p = 0; p < 4; ++p) {
            int i = i0 + p * 16;
            float4 val = *(const float4*)(src + (size_t)i * E_ + j4);
            tile[i][j4] = val.x; tile[i][j4+1] = val.y; tile[i][j4+2] = val.z; tile[i][j4+3] = val.w;
        }
        __syncthreads();
        const int s4 = (t & 15) * 4;
        const int d0 = t >> 4;
        _Float16* dst = Vt + ((size_t)bh * HD_ + db * 64) * S_ + sb * 64;
        #pragma unroll
        for (int p = 0; p < 4; ++p) {
            int d = d0 + p * 16;
            half4v pk;
            pk.x = (_Float16)tile[s4][d];   pk.y = (_Float16)tile[s4+1][d];
            pk.z = (_Float16)tile[s4+2][d]; pk.w = (_Float16)tile[s4+3][d];
            *(half4v*)(dst + (size_t)d * S_ + s4) = pk;
        }
    }
}

// ---------------- Kernel C: dbuf-K MFMA causal decay attention + fused RMSNorm ----------------
// Grid 256 = 8 heads (bh = z&7, XCD swizzle) x 32 pair-blocks; strips {u, 63-u},
// flat 33-iter pipeline over both passes. K double-buffered in LDS via register
// prefetch -> ONE barrier per iter (staging overlaps compute). V fragments read
// directly from global Vt, issued at iter start (~1500 cyc ahead of PV use).
// comb has its own LDS (dbuf must survive the pass-0 epilogue).
static constexpr int KSS  = 264;          // Ks row stride (halfs)
static constexpr int KBUF = 64 * KSS;     // halfs per K buffer (33792 B each)
static constexpr int CBS  = 265;          // comb row stride (f32)

__global__ __launch_bounds__(256, 1) void mlstm_mfma_kernel(
    const _Float16* __restrict__ Qh, const _Float16* __restrict__ Kh,
    const _Float16* __restrict__ Vt,
    const float* __restrict__ AmM, const float* __restrict__ G, const float* __restrict__ Mr,
    const float* __restrict__ rms_scale, float* __restrict__ out)
{
    __shared__ __align__(16) _Float16 Ks[2 * KBUF];       // 67584 B
    __shared__ __align__(16) _Float16 Pls[4][16 * 40];    // 5120 B
    __shared__ float comb[2 * 16 * CBS];                  // 33920 B
    __shared__ float rsum2[2][16];

    const int z  = blockIdx.x;
    const int bh = z & 7;                 // one head per XCD
    const int u  = z >> 3;                // 0..31
    const int b  = bh >> 2, h = bh & 3;
    const int t  = threadIdx.x;
    const int w  = t >> 6;
    const int l  = t & 63;
    const int col  = l & 15;
    const int quad = l >> 4;
    const int qo   = quad * 8;
    const int rw   = w & 1;               // row half
    const int cw   = w >> 1;              // col half

    const _Float16* Qp  = Qh + (size_t)bh * S_ * HD_;
    const _Float16* Kp  = Kh + (size_t)bh * S_ * HD_;
    const _Float16* Vtp = Vt + (size_t)bh * HD_ * S_;
    const float* AmMp = AmM + (size_t)bh * S_;
    const float* Gp   = G   + (size_t)bh * S_;
    const float* Mp   = Mr  + (size_t)bh * S_;
    _Float16* Pw = &Pls[w][0];

    const int T0 = (u >> 1) + 1;          // pass-0 tiles; total flat iters = 33
    const int TT = 33;
    auto c0flat = [&](int x) { return ((x < T0) ? x : (x - T0)) << 6; };

    // K register-prefetch + drain helpers
    half8 kpre[8];
    auto issueK = [&](int cN) {
        #pragma unroll
        for (int i = 0; i < 8; ++i) {
            int p = t + 256 * i;
            int row = p >> 5, ck = p & 31;
            kpre[i] = *(const half8*)(Kp + (size_t)(cN + row) * HD_ + ck * 8);
        }
    };
    auto drainTo = [&](int bsel) {
        _Float16* Kb = Ks + bsel * KBUF;
        #pragma unroll
        for (int i = 0; i < 8; ++i) {
            int p = t + 256 * i;
            int row = p >> 5, ck = p & 31;
            *(half8*)(Kb + row * KSS + ck * 8) = kpre[i];
        }
    };

    // pipeline prologue: buf0 <- tile 0, kpre <- tile 1
    issueK(c0flat(0));
    drainTo(0);
    issueK(c0flat(1));
    __syncthreads();

    int ii = 0;   // flat iteration index
    for (int pass = 0; pass < 2; ++pass) {
        const int rb = pass ? (63 - u) : u;
        const int rowbase = rb * 32 + rw * 16;

        half8 qf[8];
        #pragma unroll
        for (int kk = 0; kk < 8; ++kk)
            qf[kk] = *(const half8*)(Qp + (size_t)(rowbase + col) * HD_ + kk * 32 + qo);
        float amM[4];
        #pragma unroll
        for (int rr = 0; rr < 4; ++rr) amM[rr] = AmMp[rowbase + quad * 4 + rr];

        f32x4 acc[16];
        #pragma unroll
        for (int nn = 0; nn < 16; ++nn) acc[nn] = (f32x4){0.f, 0.f, 0.f, 0.f};
        float rs[4] = {0.f, 0.f, 0.f, 0.f};

        const int Tp = (rb >> 1) + 1;
        for (int jt = 0; jt < Tp; ++jt, ++ii) {
            const int cc = jt << 6;       // this pass's column tile
            // invariant: Ks buf[ii&1] holds tile cc; kpre holds flat tile ii+1
            if (ii + 1 < TT) drainTo((ii + 1) & 1);   // overlaps this iter's compute
            if (ii + 2 < TT) issueK(c0flat(ii + 2));

            // V fragments for THIS tile, issued early (consumed ~after QK+fixup)
            half8 vf[16];
            #pragma unroll
            for (int nn = 0; nn < 16; ++nn)
                vf[nn] = *(const half8*)(Vtp + (size_t)(nn * 16 + col) * S_ + cc + cw * 32 + qo);

            const float gv0 = Gp[cc + cw * 32 + col];
            const float gv1 = Gp[cc + cw * 32 + 16 + col];

            const _Float16* Kb = Ks + (ii & 1) * KBUF;
            f32x4 sc0 = (f32x4){0.f,0.f,0.f,0.f};
            f32x4 sc1 = (f32x4){0.f,0.f,0.f,0.f};
            #pragma unroll
            for (int kk = 0; kk < 8; ++kk) {
                half8 kf0 = *(const half8*)(Kb + (cw * 32 + col) * KSS + kk * 32 + qo);
                half8 kf1 = *(const half8*)(Kb + (cw * 32 + 16 + col) * KSS + kk * 32 + qo);
                sc0 = __builtin_amdgcn_mfma_f32_16x16x32_f16(qf[kk], kf0, sc0, 0, 0, 0);
                sc1 = __builtin_amdgcn_mfma_f32_16x16x32_f16(qf[kk], kf1, sc1, 0, 0, 0);
            }
            // fixup: p = s * exp(AmM[i]+G[j]) (one exp!), causal mask by select
            #pragma unroll
            for (int rr = 0; rr < 4; ++rr) {
                const int ig_ = rowbase + quad * 4 + rr;
                float e0 = __expf(amM[rr] + gv0);
                float e1 = __expf(amM[rr] + gv1);
                float p0 = (cc + cw * 32 + col      <= ig_) ? sc0[rr] * e0 : 0.f;
                float p1 = (cc + cw * 32 + 16 + col <= ig_) ? sc1[rr] * e1 : 0.f;
                rs[rr] += p0 + p1;
                Pw[(quad * 4 + rr) * 40 + col]      = (_Float16)p0;
                Pw[(quad * 4 + rr) * 40 + 16 + col] = (_Float16)p1;
            }
            half8 af = *(const half8*)(Pw + col * 40 + qo);   // wave-private
            // PV: acc += P(16x32) @ V(32x256)
            #pragma unroll
            for (int nn = 0; nn < 16; ++nn)
                acc[nn] = __builtin_amdgcn_mfma_f32_16x16x32_f16(af, vf[nn], acc[nn], 0, 0, 0);

            __syncthreads();   // single barrier: publishes buf[(ii+1)&1], retires buf[ii&1] reads
        }

        // ---- epilogue: combine col-halves, normalize, RMSNorm, store ----
        #pragma unroll
        for (int m = 1; m < 16; m <<= 1) {
            #pragma unroll
            for (int rr = 0; rr < 4; ++rr) rs[rr] += __shfl_xor(rs[rr], m);
        }
        if (w >= 2) {
            if (col == 0) {
                #pragma unroll
                for (int rr = 0; rr < 4; ++rr) rsum2[rw][quad * 4 + rr] = rs[rr];
            }
            #pragma unroll
            for (int nn = 0; nn < 16; ++nn)
                #pragma unroll
                for (int rr = 0; rr < 4; ++rr)
                    comb[(rw * 16 + quad * 4 + rr) * CBS + nn * 16 + col] = acc[nn][rr];
        }
        __syncthreads();
        if (w < 2) {
            float inv[4], ss[4];
            #pragma unroll
            for (int rr = 0; rr < 4; ++rr) {
                float tot = rs[rr] + rsum2[rw][quad * 4 + rr];
                float Mv = Mp[rowbase + quad * 4 + rr];
                float n = fmaxf(tot, __expf(-Mv)) + 1e-6f;
                inv[rr] = 1.0f / n;
                ss[rr] = 0.f;
            }
            #pragma unroll
            for (int nn = 0; nn < 16; ++nn) {
                #pragma unroll
                for (int rr = 0; rr < 4; ++rr) {
                    float hv = (acc[nn][rr] +
                                comb[(rw * 16 + quad * 4 + rr) * CBS + nn * 16 + col]) * inv[rr];
                    acc[nn][rr] = hv;
                    ss[rr] = fmaf(hv, hv, ss[rr]);
                }
            }
            #pragma unroll
            for (int m = 1; m < 16; m <<= 1) {
                #pragma unroll
                for (int rr = 0; rr < 4; ++rr) ss[rr] += __shfl_xor(ss[rr], m);
            }
            #pragma unroll
            for (int rr = 0; rr < 4; ++rr) {
                float rstd = rsqrtf(ss[rr] * (1.0f / HD_) + 1e-6f);
                float* orow = out + ((size_t)(b * S_ + rowbase + quad * 4 + rr)) * E_ + h * HD_;
                #pragma unroll
                for (int nn = 0; nn < 16; ++nn)
                    orow[nn * 16 + col] = acc[nn][rr] * rstd * (1.0f + rms_scale[nn * 16 + col]);
            }
        }
        __syncthreads();   // epilogue fully done before next pass reuses rsum2/comb
    }
}

extern "C" void kernel_launch(void* const* d_in, const int* in_sizes, int n_in,
                              void* d_out, int out_size, void* d_ws, size_t ws_size,
                              hipStream_t stream) {
    (void)in_sizes; (void)n_in; (void)out_size; (void)ws_size;
    const float* q   = (const float*)d_in[0];
    const float* k   = (const float*)d_in[1];
    const float* v   = (const float*)d_in[2];
    const float* igk = (const float*)d_in[3];
    const float* igb = (const float*)d_in[4];
    const float* fgk = (const float*)d_in[5];
    const float* fgb = (const float*)d_in[6];
    const float* rsc = (const float*)d_in[7];
    float* out = (float*)d_out;

    float* ws  = (float*)d_ws;
    float* ig  = ws;                          // BH*S each
    float* fg  = ws + (size_t)BH_ * S_;
    float* AmM = ws + (size_t)2 * BH_ * S_;
    float* G   = ws + (size_t)3 * BH_ * S_;
    float* M   = ws + (size_t)4 * BH_ * S_;
    _Float16* Qh = (_Float16*)(ws + (size_t)5 * BH_ * S_);
    _Float16* Kh = Qh + (size_t)BH_ * S_ * HD_;
    _Float16* Vt = Kh + (size_t)BH_ * S_ * HD_;

    gates_kernel<<<B_ * S_ / 16, 1024, 0, stream>>>(q, k, v, igk, igb, fgk, fgb, ig, fg, Qh, Kh);
    scan_transpose_kernel<<<8 + BH_ * 32 * 4, 256, 0, stream>>>(ig, fg, AmM, G, M, v, Vt);
    mlstm_mfma_kernel<<<BH_ * 32, 256, 0, stream>>>(Qh, Kh, Vt, AmM, G, M, rsc, out);
}

// Round 11
// 186.435 us; speedup vs baseline: 1.1230x; 1.1230x over previous
//
#include <hip/hip_runtime.h>
#include <math.h>

static constexpr int B_  = 2;
static constexpr int S_  = 2048;
static constexpr int E_  = 1024;
static constexpr int NH_ = 4;
static constexpr int HD_ = 256;
static constexpr int BH_ = B_ * NH_;

typedef __attribute__((ext_vector_type(8))) _Float16 half8;
typedef __attribute__((ext_vector_type(4))) float    f32x4;
typedef __attribute__((ext_vector_type(4))) _Float16 half4v;

// ---------------- Kernel 1: gates + fp16 Q/K + V-transpose (fused) ----------------
// 256 blocks x 1024 threads. Part A: R7-validated gates (weights LDS-staged,
// 16 waves x 1 row). Part B: R7-validated V-transpose, 4 tiles/block in the
// re-used weight LDS (4 x 16640 B <= 98304 B).
__global__ __launch_bounds__(1024) void prep_kernel(
    const float* __restrict__ q, const float* __restrict__ k, const float* __restrict__ v,
    const float* __restrict__ igk, const float* __restrict__ igb,
    const float* __restrict__ fgk, const float* __restrict__ fgb,
    float* __restrict__ ig_out, float* __restrict__ fg_out,
    _Float16* __restrict__ Qh, _Float16* __restrict__ Kh, _Float16* __restrict__ Vt)
{
    __shared__ __align__(16) char PSM[98304];
    float4* wi = (float4*)PSM;          // [3072] 48 KB
    float4* wf = wi + 3 * E_;           // [3072] 48 KB

    const int t = threadIdx.x;
    // ---- Part A: stage weights ----
    #pragma unroll
    for (int i = 0; i < 3; ++i) {
        int e = t + 1024 * i;
        wi[e] = ((const float4*)igk)[e];
        wf[e] = ((const float4*)fgk)[e];
    }
    __syncthreads();

    const int wave = t >> 6;
    const int l    = t & 63;
    const int bs   = blockIdx.x * 16 + wave;     // b*S + s
    const int b = bs >> 11, s = bs & (S_ - 1);
    const float* qrow = q + (size_t)bs * E_;
    const float* krow = k + (size_t)bs * E_;
    const float* vrow = v + (size_t)bs * E_;

    float accI[4] = {0.f,0.f,0.f,0.f}, accF[4] = {0.f,0.f,0.f,0.f};
    #pragma unroll
    for (int j = 0; j < 48; ++j) {
        const int e = l + 64 * j;
        float g;
        if (j < 16)       g = qrow[e];
        else if (j < 32)  g = krow[e - E_];
        else              g = vrow[e - 2 * E_];
        if (j < 16) {
            int hh = e >> 8, d = e & 255;
            Qh[(((size_t)(b * NH_ + hh)) * S_ + s) * HD_ + d] = (_Float16)(g * 0.0625f);
        } else if (j < 32) {
            int e2 = e - E_; int hh = e2 >> 8, d = e2 & 255;
            Kh[(((size_t)(b * NH_ + hh)) * S_ + s) * HD_ + d] = (_Float16)g;
        }
        float4 wiv = wi[e];
        float4 wfv = wf[e];
        accI[0] = fmaf(g, wiv.x, accI[0]); accI[1] = fmaf(g, wiv.y, accI[1]);
        accI[2] = fmaf(g, wiv.z, accI[2]); accI[3] = fmaf(g, wiv.w, accI[3]);
        accF[0] = fmaf(g, wfv.x, accF[0]); accF[1] = fmaf(g, wfv.y, accF[1]);
        accF[2] = fmaf(g, wfv.z, accF[2]); accF[3] = fmaf(g, wfv.w, accF[3]);
    }
    #pragma unroll
    for (int m = 1; m < 64; m <<= 1) {
        #pragma unroll
        for (int h = 0; h < 4; ++h) {
            accI[h] += __shfl_xor(accI[h], m);
            accF[h] += __shfl_xor(accF[h], m);
        }
    }
    if (l == 0) {
        #pragma unroll
        for (int h = 0; h < 4; ++h) {
            ig_out[((size_t)(b * NH_ + h)) * S_ + s] = accI[h] + igb[h];
            fg_out[((size_t)(b * NH_ + h)) * S_ + s] = accF[h] + fgb[h];
        }
    }

    // ---- Part B: V transpose (4 tiles per block; LDS reused) ----
    __syncthreads();    // all weight reads done
    {
        float (*tile)[65] = (float(*)[65])(PSM + (t >> 8) * 16640);
        const int tid = t & 255;
        const int m  = blockIdx.x * 4 + (t >> 8);    // 0..1023
        const int bh = m & 7;
        const int sb = (m >> 3) & 31;
        const int db = m >> 8;
        const int bb = bh >> 2, hh = bh & 3;
        const int j4 = (tid & 15) * 4;
        const int i0 = tid >> 4;
        const float* src = v + ((size_t)(bb * S_ + sb * 64)) * E_ + hh * HD_ + db * 64;
        #pragma unroll
        for (int p = 0; p < 4; ++p) {
            int i = i0 + p * 16;
            float4 val = *(const float4*)(src + (size_t)i * E_ + j4);
            tile[i][j4] = val.x; tile[i][j4+1] = val.y; tile[i][j4+2] = val.z; tile[i][j4+3] = val.w;
        }
        __syncthreads();
        const int s4 = (tid & 15) * 4;
        const int d0 = tid >> 4;
        _Float16* dst = Vt + ((size_t)bh * HD_ + db * 64) * S_ + sb * 64;
        #pragma unroll
        for (int p = 0; p < 4; ++p) {
            int d = d0 + p * 16;
            half4v pk;
            pk.x = (_Float16)tile[s4][d];   pk.y = (_Float16)tile[s4+1][d];
            pk.z = (_Float16)tile[s4+2][d]; pk.w = (_Float16)tile[s4+3][d];
            *(half4v*)(dst + (size_t)d * S_ + s4) = pk;
        }
    }
}

// ---------------- Kernel 2: in-block scan + R7 mlstm + fused RMSNorm ----------------
// Grid 256 = 8 heads (bh = z&7, XCD swizzle) x 32 pair-blocks {u, 63-u}.
// Prologue: each block recomputes its head's AmM/G/M scan from ig/fg into LDS
// (redundant x32, fully parallel; removes the serial 8-block scan dispatch).
// Main loop: exact R7 structure (82 us known-good): K+V staged via register
// prefetch -> LDS, 2 barriers/iter, P round-trip, fused epilogue.
static constexpr int KSS = 264;   // Ks row stride (halfs)
static constexpr int VSS = 72;    // Vs row stride (halfs)
static constexpr int CBS = 265;   // comb row stride (f32)
static constexpr int OFF_PLS  = 64 * KSS * 2 + 256 * VSS * 2;   // 70656
static constexpr int OFF_RS2  = OFF_PLS + 4 * 640 * 2;          // 75776
static constexpr int OFF_AMM  = OFF_RS2 + 128;                  // 75904
static constexpr int OFF_G    = OFF_AMM + S_ * 4;               // 84096
static constexpr int OFF_M    = OFF_G   + S_ * 4;               // 92288
static constexpr int SMB      = OFF_M   + S_ * 4;               // 100480

__global__ __launch_bounds__(256, 1) void mlstm_kernel(
    const _Float16* __restrict__ Qh, const _Float16* __restrict__ Kh,
    const _Float16* __restrict__ Vt,
    const float* __restrict__ ig, const float* __restrict__ fg,
    const float* __restrict__ rms_scale, float* __restrict__ out)
{
    __shared__ __align__(16) char SMEM[SMB];
    _Float16* Ks    = (_Float16*)SMEM;                   // [64][KSS] (also scan sc alias)
    _Float16* Vs    = (_Float16*)(SMEM + 64 * KSS * 2);  // [256][VSS]
    float*    comb  = (float*)SMEM;                      // aliased over Ks/Vs
    float*    rsum2 = (float*)(SMEM + OFF_RS2);          // [2][16]
    float*    sAmM  = (float*)(SMEM + OFF_AMM);          // [S]
    float*    sG    = (float*)(SMEM + OFF_G);            // [S]
    float*    sM    = (float*)(SMEM + OFF_M);            // [S]
    _Float16* Pls   = (_Float16*)(SMEM + OFF_PLS);

    const int z  = blockIdx.x;
    const int bh = z & 7;                 // one head per XCD
    const int u  = z >> 3;                // 0..31
    const int b  = bh >> 2, h = bh & 3;
    const int t  = threadIdx.x;
    const int w  = t >> 6;
    const int l  = t & 63;
    const int col  = l & 15;
    const int quad = l >> 4;
    const int qo   = quad * 8;
    const int rw   = w & 1;               // row half
    const int cw   = w >> 1;              // col half

    // ---- scan prologue: head-local AmM/G/M into LDS ----
    {
        float* sc = (float*)SMEM;         // 1 KB, aliased in Ks region
        const float* fgp = fg + (size_t)bh * S_;
        const float* igp = ig + (size_t)bh * S_;
        float ls[8];
        float run = 0.f;
        #pragma unroll
        for (int i = 0; i < 8; ++i) {
            float x = fgp[t * 8 + i];
            float lg = (x >= 0.f) ? -log1pf(expf(-x)) : (x - log1pf(expf(x)));
            run += lg;
            ls[i] = run;
        }
        sc[t] = run;
        __syncthreads();
        for (int off = 1; off < 256; off <<= 1) {
            float vv = (t >= off) ? sc[t - off] : 0.f;
            __syncthreads();
            sc[t] += vv;
            __syncthreads();
        }
        float excl = sc[t] - run;
        float A[8], g[8], gm[8];
        #pragma unroll
        for (int i = 0; i < 8; ++i) A[i] = excl + ls[i];
        float rmax = -__builtin_inff();
        #pragma unroll
        for (int i = 0; i < 8; ++i) {
            g[i] = igp[t * 8 + i] - A[i];
            rmax = fmaxf(rmax, g[i]);
            gm[i] = rmax;
        }
        __syncthreads();
        sc[t] = rmax;
        __syncthreads();
        for (int off = 1; off < 256; off <<= 1) {
            float vv = (t >= off) ? sc[t - off] : -__builtin_inff();
            __syncthreads();
            sc[t] = fmaxf(sc[t], vv);
            __syncthreads();
        }
        float exm = (t == 0) ? -__builtin_inff() : sc[t - 1];
        #pragma unroll
        for (int i = 0; i < 8; ++i) {
            float cm = fmaxf(exm, gm[i]);
            float Mi = A[i] + cm;
            sAmM[t * 8 + i] = A[i] - Mi;
            sG[t * 8 + i]   = g[i];
            sM[t * 8 + i]   = Mi;
        }
        __syncthreads();   // sAmM/sG/sM visible to all; sc alias retired
    }

    const _Float16* Qp  = Qh + (size_t)bh * S_ * HD_;
    const _Float16* Kp  = Kh + (size_t)bh * S_ * HD_;
    const _Float16* Vtp = Vt + (size_t)bh * HD_ * S_;
    _Float16* Pw = Pls + w * 640;

    half8 kpre[8], vpre[8];
    auto issueK = [&](int c0n) {
        #pragma unroll
        for (int i = 0; i < 8; ++i) {
            int p = t + 256 * i;
            int row = p >> 5, ck = p & 31;
            kpre[i] = *(const half8*)(Kp + (size_t)(c0n + row) * HD_ + ck * 8);
        }
    };
    auto issueV = [&](int c0n) {
        #pragma unroll
        for (int i = 0; i < 8; ++i) {
            int p = t + 256 * i;
            int n = p >> 3, ch = p & 7;
            vpre[i] = *(const half8*)(Vtp + (size_t)n * S_ + c0n + ch * 8);
        }
    };

    issueK(0);
    issueV(0);

    for (int pass = 0; pass < 2; ++pass) {
        const int rb = pass ? (63 - u) : u;
        const int rowbase = rb * 32 + rw * 16;

        half8 qf[8];
        #pragma unroll
        for (int kk = 0; kk < 8; ++kk)
            qf[kk] = *(const half8*)(Qp + (size_t)(rowbase + col) * HD_ + kk * 32 + qo);
        float amM[4];
        #pragma unroll
        for (int rr = 0; rr < 4; ++rr) amM[rr] = sAmM[rowbase + quad * 4 + rr];

        f32x4 acc[16];
        #pragma unroll
        for (int nn = 0; nn < 16; ++nn) acc[nn] = (f32x4){0.f, 0.f, 0.f, 0.f};
        float rs[4] = {0.f, 0.f, 0.f, 0.f};

        const int Tt = (rb >> 1) + 1;
        for (int jt = 0; jt < Tt; ++jt) {
            const int c0 = jt << 6;
            __syncthreads();              // prior-iter frag reads / epilogue done
            #pragma unroll
            for (int i = 0; i < 8; ++i) { // drain K prefetch (vmcnt wait here)
                int p = t + 256 * i;
                int row = p >> 5, ck = p & 31;
                *(half8*)(Ks + row * KSS + ck * 8) = kpre[i];
            }
            #pragma unroll
            for (int i = 0; i < 8; ++i) { // drain V prefetch
                int p = t + 256 * i;
                int n = p >> 3, ch = p & 7;
                *(half8*)(Vs + n * VSS + ch * 8) = vpre[i];
            }
            __syncthreads();
            if (!(pass == 1 && jt + 1 == Tt)) {
                const int cn = (jt + 1 < Tt) ? (c0 + 64) : 0;
                issueK(cn);
                issueV(cn);
            }
            // QK^T on this wave's 16 rows x 32 cols
            const float gv0 = sG[c0 + cw * 32 + col];
            const float gv1 = sG[c0 + cw * 32 + 16 + col];
            f32x4 sc0 = (f32x4){0.f,0.f,0.f,0.f};
            f32x4 sc1 = (f32x4){0.f,0.f,0.f,0.f};
            #pragma unroll
            for (int kk = 0; kk < 8; ++kk) {
                half8 kf0 = *(const half8*)(Ks + (cw * 32 + col) * KSS + kk * 32 + qo);
                half8 kf1 = *(const half8*)(Ks + (cw * 32 + 16 + col) * KSS + kk * 32 + qo);
                sc0 = __builtin_amdgcn_mfma_f32_16x16x32_f16(qf[kk], kf0, sc0, 0, 0, 0);
                sc1 = __builtin_amdgcn_mfma_f32_16x16x32_f16(qf[kk], kf1, sc1, 0, 0, 0);
            }
            // fixup: p = s * exp(AmM[i]+G[j]) (one exp!), causal mask by select
            #pragma unroll
            for (int rr = 0; rr < 4; ++rr) {
                const int ig_ = rowbase + quad * 4 + rr;
                float e0 = __expf(amM[rr] + gv0);
                float e1 = __expf(amM[rr] + gv1);
                float p0 = (c0 + cw * 32 + col      <= ig_) ? sc0[rr] * e0 : 0.f;
                float p1 = (c0 + cw * 32 + 16 + col <= ig_) ? sc1[rr] * e1 : 0.f;
                rs[rr] += p0 + p1;
                Pw[(quad * 4 + rr) * 40 + col]      = (_Float16)p0;
                Pw[(quad * 4 + rr) * 40 + 16 + col] = (_Float16)p1;
            }
            half8 af = *(const half8*)(Pw + col * 40 + qo);   // wave-private
            // PV: acc += P(16x32) @ V(32x256)
            #pragma unroll
            for (int nn = 0; nn < 16; ++nn) {
                half8 vf = *(const half8*)(Vs + (nn * 16 + col) * VSS + cw * 32 + qo);
                acc[nn] = __builtin_amdgcn_mfma_f32_16x16x32_f16(af, vf, acc[nn], 0, 0, 0);
            }
        }

        // epilogue: combine col-halves, normalize, RMSNorm, store
        #pragma unroll
        for (int m = 1; m < 16; m <<= 1) {
            #pragma unroll
            for (int rr = 0; rr < 4; ++rr) rs[rr] += __shfl_xor(rs[rr], m);
        }
        __syncthreads();                  // all frag reads done; safe to alias comb
        if (w >= 2) {
            if (col == 0) {
                #pragma unroll
                for (int rr = 0; rr < 4; ++rr) rsum2[rw * 16 + quad * 4 + rr] = rs[rr];
            }
            #pragma unroll
            for (int nn = 0; nn < 16; ++nn)
                #pragma unroll
                for (int rr = 0; rr < 4; ++rr)
                    comb[(rw * 16 + quad * 4 + rr) * CBS + nn * 16 + col] = acc[nn][rr];
        }
        __syncthreads();
        if (w < 2) {
            float inv[4], ss[4];
            #pragma unroll
            for (int rr = 0; rr < 4; ++rr) {
                float tot = rs[rr] + rsum2[rw * 16 + quad * 4 + rr];
                float Mv = sM[rowbase + quad * 4 + rr];
                float n = fmaxf(tot, __expf(-Mv)) + 1e-6f;
                inv[rr] = 1.0f / n;
                ss[rr] = 0.f;
            }
            #pragma unroll
            for (int nn = 0; nn < 16; ++nn) {
                #pragma unroll
                for (int rr = 0; rr < 4; ++rr) {
                    float hv = (acc[nn][rr] +
                                comb[(rw * 16 + quad * 4 + rr) * CBS + nn * 16 + col]) * inv[rr];
                    acc[nn][rr] = hv;
                    ss[rr] = fmaf(hv, hv, ss[rr]);
                }
            }
            #pragma unroll
            for (int m = 1; m < 16; m <<= 1) {
                #pragma unroll
                for (int rr = 0; rr < 4; ++rr) ss[rr] += __shfl_xor(ss[rr], m);
            }
            #pragma unroll
            for (int rr = 0; rr < 4; ++rr) {
                float rstd = rsqrtf(ss[rr] * (1.0f / HD_) + 1e-6f);
                float* orow = out + ((size_t)(b * S_ + rowbase + quad * 4 + rr)) * E_ + h * HD_;
                #pragma unroll
                for (int nn = 0; nn < 16; ++nn)
                    orow[nn * 16 + col] = acc[nn][rr] * rstd * (1.0f + rms_scale[nn * 16 + col]);
            }
        }
        __syncthreads();   // epilogue done before next pass reuses comb/rsum2
    }
}

extern "C" void kernel_launch(void* const* d_in, const int* in_sizes, int n_in,
                              void* d_out, int out_size, void* d_ws, size_t ws_size,
                              hipStream_t stream) {
    (void)in_sizes; (void)n_in; (void)out_size; (void)ws_size;
    const float* q   = (const float*)d_in[0];
    const float* k   = (const float*)d_in[1];
    const float* v   = (const float*)d_in[2];
    const float* igk = (const float*)d_in[3];
    const float* igb = (const float*)d_in[4];
    const float* fgk = (const float*)d_in[5];
    const float* fgb = (const float*)d_in[6];
    const float* rsc = (const float*)d_in[7];
    float* out = (float*)d_out;

    float* ws  = (float*)d_ws;
    float* ig  = ws;                          // BH*S each
    float* fg  = ws + (size_t)BH_ * S_;
    _Float16* Qh = (_Float16*)(ws + (size_t)2 * BH_ * S_);
    _Float16* Kh = Qh + (size_t)BH_ * S_ * HD_;
    _Float16* Vt = Kh + (size_t)BH_ * S_ * HD_;

    prep_kernel<<<B_ * S_ / 16, 1024, 0, stream>>>(q, k, v, igk, igb, fgk, fgb,
                                                   ig, fg, Qh, Kh, Vt);
    mlstm_kernel<<<BH_ * 32, 256, 0, stream>>>(Qh, Kh, Vt, ig, fg, rsc, out);
}

// Round 12
// 168.487 us; speedup vs baseline: 1.2426x; 1.1065x over previous
//
#include <hip/hip_runtime.h>
#include <math.h>

static constexpr int B_  = 2;
static constexpr int S_  = 2048;
static constexpr int E_  = 1024;
static constexpr int NH_ = 4;
static constexpr int HD_ = 256;
static constexpr int BH_ = B_ * NH_;

typedef __attribute__((ext_vector_type(8))) _Float16 half8;
typedef __attribute__((ext_vector_type(4))) float    f32x4;
typedef __attribute__((ext_vector_type(4))) _Float16 half4v;

// ---------------- Kernel 1: gates + fp16 Q/K + V-transpose (fused; unchanged R11) ----------------
__global__ __launch_bounds__(1024) void prep_kernel(
    const float* __restrict__ q, const float* __restrict__ k, const float* __restrict__ v,
    const float* __restrict__ igk, const float* __restrict__ igb,
    const float* __restrict__ fgk, const float* __restrict__ fgb,
    float* __restrict__ ig_out, float* __restrict__ fg_out,
    _Float16* __restrict__ Qh, _Float16* __restrict__ Kh, _Float16* __restrict__ Vt)
{
    __shared__ __align__(16) char PSM[98304];
    float4* wi = (float4*)PSM;          // [3072] 48 KB
    float4* wf = wi + 3 * E_;           // [3072] 48 KB

    const int t = threadIdx.x;
    #pragma unroll
    for (int i = 0; i < 3; ++i) {
        int e = t + 1024 * i;
        wi[e] = ((const float4*)igk)[e];
        wf[e] = ((const float4*)fgk)[e];
    }
    __syncthreads();

    const int wave = t >> 6;
    const int l    = t & 63;
    const int bs   = blockIdx.x * 16 + wave;     // b*S + s
    const int b = bs >> 11, s = bs & (S_ - 1);
    const float* qrow = q + (size_t)bs * E_;
    const float* krow = k + (size_t)bs * E_;
    const float* vrow = v + (size_t)bs * E_;

    float accI[4] = {0.f,0.f,0.f,0.f}, accF[4] = {0.f,0.f,0.f,0.f};
    #pragma unroll
    for (int j = 0; j < 48; ++j) {
        const int e = l + 64 * j;
        float g;
        if (j < 16)       g = qrow[e];
        else if (j < 32)  g = krow[e - E_];
        else              g = vrow[e - 2 * E_];
        if (j < 16) {
            int hh = e >> 8, d = e & 255;
            Qh[(((size_t)(b * NH_ + hh)) * S_ + s) * HD_ + d] = (_Float16)(g * 0.0625f);
        } else if (j < 32) {
            int e2 = e - E_; int hh = e2 >> 8, d = e2 & 255;
            Kh[(((size_t)(b * NH_ + hh)) * S_ + s) * HD_ + d] = (_Float16)g;
        }
        float4 wiv = wi[e];
        float4 wfv = wf[e];
        accI[0] = fmaf(g, wiv.x, accI[0]); accI[1] = fmaf(g, wiv.y, accI[1]);
        accI[2] = fmaf(g, wiv.z, accI[2]); accI[3] = fmaf(g, wiv.w, accI[3]);
        accF[0] = fmaf(g, wfv.x, accF[0]); accF[1] = fmaf(g, wfv.y, accF[1]);
        accF[2] = fmaf(g, wfv.z, accF[2]); accF[3] = fmaf(g, wfv.w, accF[3]);
    }
    #pragma unroll
    for (int m = 1; m < 64; m <<= 1) {
        #pragma unroll
        for (int h = 0; h < 4; ++h) {
            accI[h] += __shfl_xor(accI[h], m);
            accF[h] += __shfl_xor(accF[h], m);
        }
    }
    if (l == 0) {
        #pragma unroll
        for (int h = 0; h < 4; ++h) {
            ig_out[((size_t)(b * NH_ + h)) * S_ + s] = accI[h] + igb[h];
            fg_out[((size_t)(b * NH_ + h)) * S_ + s] = accF[h] + fgb[h];
        }
    }

    __syncthreads();    // all weight reads done; reuse LDS for transpose
    {
        float (*tile)[65] = (float(*)[65])(PSM + (t >> 8) * 16640);
        const int tid = t & 255;
        const int m  = blockIdx.x * 4 + (t >> 8);    // 0..1023
        const int bh = m & 7;
        const int sb = (m >> 3) & 31;
        const int db = m >> 8;
        const int bb = bh >> 2, hh = bh & 3;
        const int j4 = (tid & 15) * 4;
        const int i0 = tid >> 4;
        const float* src = v + ((size_t)(bb * S_ + sb * 64)) * E_ + hh * HD_ + db * 64;
        #pragma unroll
        for (int p = 0; p < 4; ++p) {
            int i = i0 + p * 16;
            float4 val = *(const float4*)(src + (size_t)i * E_ + j4);
            tile[i][j4] = val.x; tile[i][j4+1] = val.y; tile[i][j4+2] = val.z; tile[i][j4+3] = val.w;
        }
        __syncthreads();
        const int s4 = (tid & 15) * 4;
        const int d0 = tid >> 4;
        _Float16* dst = Vt + ((size_t)bh * HD_ + db * 64) * S_ + sb * 64;
        #pragma unroll
        for (int p = 0; p < 4; ++p) {
            int d = d0 + p * 16;
            half4v pk;
            pk.x = (_Float16)tile[s4][d];   pk.y = (_Float16)tile[s4+1][d];
            pk.z = (_Float16)tile[s4+2][d]; pk.w = (_Float16)tile[s4+3][d];
            *(half4v*)(dst + (size_t)d * S_ + s4) = pk;
        }
    }
}

// ---------------- Kernel 2: 8-wave mlstm (2 waves/SIMD) + in-block scan + RMSNorm ----------------
// Grid 256 = 8 heads (bh = z&7) x 32 pair-blocks {u, 63-u}; 512 threads = 8 waves.
// Wave (rw,cq) = (row-half, col-quarter): QK -> 16x16 P quarter -> shared P buf;
// PV is an n-split (each wave owns an exclusive 64-wide n-slice, acc = 16 VGPRs).
// 2 waves/SIMD hide ds_read->MFMA and drain-vmcnt latency (m114 co-scheduling).
static constexpr int KSS = 264;   // Ks row stride (halfs)
static constexpr int VSS = 72;    // Vs row stride (halfs)
static constexpr int PBS = 72;    // P buf row stride (halfs)
static constexpr int OFF_VS  = 64 * KSS * 2;            // 33792
static constexpr int OFF_PB  = OFF_VS + 256 * VSS * 2;  // 70656
static constexpr int OFF_RSE = OFF_PB + 2 * 16 * PBS * 2; // 75264
static constexpr int OFF_SSE = OFF_RSE + 512;           // 75776
static constexpr int OFF_AMM = OFF_SSE + 512;           // 76288
static constexpr int OFF_G   = OFF_AMM + S_ * 4;        // 84480
static constexpr int OFF_M   = OFF_G   + S_ * 4;        // 92672
static constexpr int SMB     = OFF_M   + S_ * 4;        // 100864

__global__ __launch_bounds__(512, 2) void mlstm_kernel(
    const _Float16* __restrict__ Qh, const _Float16* __restrict__ Kh,
    const _Float16* __restrict__ Vt,
    const float* __restrict__ ig, const float* __restrict__ fg,
    const float* __restrict__ rms_scale, float* __restrict__ out)
{
    __shared__ __align__(16) char SMEM[SMB];
    _Float16* Ks    = (_Float16*)SMEM;                   // [64][KSS]
    _Float16* Vs    = (_Float16*)(SMEM + OFF_VS);        // [256][VSS]
    _Float16* Pb    = (_Float16*)(SMEM + OFF_PB);        // [2][16][PBS]
    float*    rsumE = (float*)(SMEM + OFF_RSE);          // [2][4][16]
    float*    ssE   = (float*)(SMEM + OFF_SSE);          // [2][4][16]
    float*    sAmM  = (float*)(SMEM + OFF_AMM);          // [S]
    float*    sG    = (float*)(SMEM + OFF_G);            // [S]
    float*    sM    = (float*)(SMEM + OFF_M);            // [S]

    const int z  = blockIdx.x;
    const int bh = z & 7;                 // one head per XCD
    const int u  = z >> 3;                // 0..31
    const int b  = bh >> 2, h = bh & 3;
    const int t  = threadIdx.x;
    const int w  = t >> 6;                // 0..7
    const int l  = t & 63;
    const int col  = l & 15;
    const int quad = l >> 4;
    const int qo   = quad * 8;
    const int rw   = w >> 2;              // row half (16 rows)
    const int cq   = w & 3;               // col quarter (16 of 64 cols)

    // ---- scan prologue: head-local AmM/G/M into LDS (512 threads x 4 elems) ----
    {
        float* sc = (float*)SMEM;         // 2 KB, aliased in Ks region
        const float* fgp = fg + (size_t)bh * S_;
        const float* igp = ig + (size_t)bh * S_;
        float ls[4];
        float run = 0.f;
        #pragma unroll
        for (int i = 0; i < 4; ++i) {
            float x = fgp[t * 4 + i];
            float lg = (x >= 0.f) ? -log1pf(expf(-x)) : (x - log1pf(expf(x)));
            run += lg;
            ls[i] = run;
        }
        sc[t] = run;
        __syncthreads();
        for (int off = 1; off < 512; off <<= 1) {
            float vv = (t >= off) ? sc[t - off] : 0.f;
            __syncthreads();
            sc[t] += vv;
            __syncthreads();
        }
        float excl = sc[t] - run;
        float A[4], g[4], gm[4];
        #pragma unroll
        for (int i = 0; i < 4; ++i) A[i] = excl + ls[i];
        float rmax = -__builtin_inff();
        #pragma unroll
        for (int i = 0; i < 4; ++i) {
            g[i] = igp[t * 4 + i] - A[i];
            rmax = fmaxf(rmax, g[i]);
            gm[i] = rmax;
        }
        __syncthreads();
        sc[t] = rmax;
        __syncthreads();
        for (int off = 1; off < 512; off <<= 1) {
            float vv = (t >= off) ? sc[t - off] : -__builtin_inff();
            __syncthreads();
            sc[t] = fmaxf(sc[t], vv);
            __syncthreads();
        }
        float exm = (t == 0) ? -__builtin_inff() : sc[t - 1];
        #pragma unroll
        for (int i = 0; i < 4; ++i) {
            float cm = fmaxf(exm, gm[i]);
            float Mi = A[i] + cm;
            sAmM[t * 4 + i] = A[i] - Mi;
            sG[t * 4 + i]   = g[i];
            sM[t * 4 + i]   = Mi;
        }
        __syncthreads();   // sAmM/sG/sM visible; sc alias retired
    }

    const _Float16* Qp  = Qh + (size_t)bh * S_ * HD_;
    const _Float16* Kp  = Kh + (size_t)bh * S_ * HD_;
    const _Float16* Vtp = Vt + (size_t)bh * HD_ * S_;
    _Float16* Pbr = Pb + rw * 16 * PBS;

    half8 kpre[4], vpre[4];
    auto issueK = [&](int c0n) {
        #pragma unroll
        for (int i = 0; i < 4; ++i) {
            int p = t + 512 * i;
            int row = p >> 5, ck = p & 31;
            kpre[i] = *(const half8*)(Kp + (size_t)(c0n + row) * HD_ + ck * 8);
        }
    };
    auto issueV = [&](int c0n) {
        #pragma unroll
        for (int i = 0; i < 4; ++i) {
            int p = t + 512 * i;
            int n = p >> 3, ch = p & 7;
            vpre[i] = *(const half8*)(Vtp + (size_t)n * S_ + c0n + ch * 8);
        }
    };

    issueK(0);
    issueV(0);

    for (int pass = 0; pass < 2; ++pass) {
        const int rb = pass ? (63 - u) : u;
        const int rowbase = rb * 32 + rw * 16;

        half8 qf[8];
        #pragma unroll
        for (int kk = 0; kk < 8; ++kk)
            qf[kk] = *(const half8*)(Qp + (size_t)(rowbase + col) * HD_ + kk * 32 + qo);
        float amM[4];
        #pragma unroll
        for (int rr = 0; rr < 4; ++rr) amM[rr] = sAmM[rowbase + quad * 4 + rr];

        f32x4 acc[4];
        #pragma unroll
        for (int nn = 0; nn < 4; ++nn) acc[nn] = (f32x4){0.f, 0.f, 0.f, 0.f};
        float rs[4] = {0.f, 0.f, 0.f, 0.f};

        const int Tt = (rb >> 1) + 1;
        for (int jt = 0; jt < Tt; ++jt) {
            const int c0 = jt << 6;
            __syncthreads();              // prior-iter Ks/Vs/Pb reads done
            #pragma unroll
            for (int i = 0; i < 4; ++i) { // drain K prefetch (vmcnt wait here)
                int p = t + 512 * i;
                int row = p >> 5, ck = p & 31;
                *(half8*)(Ks + row * KSS + ck * 8) = kpre[i];
            }
            #pragma unroll
            for (int i = 0; i < 4; ++i) { // drain V prefetch
                int p = t + 512 * i;
                int n = p >> 3, ch = p & 7;
                *(half8*)(Vs + n * VSS + ch * 8) = vpre[i];
            }
            __syncthreads();
            if (!(pass == 1 && jt + 1 == Tt)) {
                const int cn = (jt + 1 < Tt) ? (c0 + 64) : 0;
                issueK(cn);
                issueV(cn);
            }
            // ---- QK^T: this wave's 16 rows x 16 cols (quarter cq) ----
            const float gv = sG[c0 + cq * 16 + col];
            f32x4 sc0 = (f32x4){0.f,0.f,0.f,0.f};
            #pragma unroll
            for (int kk = 0; kk < 8; ++kk) {
                half8 kf = *(const half8*)(Ks + (cq * 16 + col) * KSS + kk * 32 + qo);
                sc0 = __builtin_amdgcn_mfma_f32_16x16x32_f16(qf[kk], kf, sc0, 0, 0, 0);
            }
            // ---- fixup: p = s * exp(AmM[i]+G[j]) (one exp!), mask by select ----
            #pragma unroll
            for (int rr = 0; rr < 4; ++rr) {
                const int ig_ = rowbase + quad * 4 + rr;
                float e0 = __expf(amM[rr] + gv);
                float p0 = (c0 + cq * 16 + col <= ig_) ? sc0[rr] * e0 : 0.f;
                rs[rr] += p0;
                Pbr[(quad * 4 + rr) * PBS + cq * 16 + col] = (_Float16)p0;
            }
            __syncthreads();              // publish P (cross-wave within row-half)
            // ---- PV n-split: A = P[rw](16x64), B = Vs n-slice, k = 64 ----
            half8 af0 = *(const half8*)(Pbr + col * PBS + qo);
            half8 af1 = *(const half8*)(Pbr + col * PBS + 32 + qo);
            #pragma unroll
            for (int nn = 0; nn < 4; ++nn) {
                const int n = cq * 64 + nn * 16 + col;
                half8 vf0 = *(const half8*)(Vs + n * VSS + qo);
                half8 vf1 = *(const half8*)(Vs + n * VSS + 32 + qo);
                acc[nn] = __builtin_amdgcn_mfma_f32_16x16x32_f16(af0, vf0, acc[nn], 0, 0, 0);
                acc[nn] = __builtin_amdgcn_mfma_f32_16x16x32_f16(af1, vf1, acc[nn], 0, 0, 0);
            }
        }

        // ---- epilogue: rowsum across quarters, normalize, RMSNorm, store slice ----
        #pragma unroll
        for (int m = 1; m < 16; m <<= 1) {
            #pragma unroll
            for (int rr = 0; rr < 4; ++rr) rs[rr] += __shfl_xor(rs[rr], m);
        }
        if (col == 0) {
            #pragma unroll
            for (int rr = 0; rr < 4; ++rr)
                rsumE[rw * 64 + cq * 16 + quad * 4 + rr] = rs[rr];
        }
        __syncthreads();
        float inv[4], ss[4];
        #pragma unroll
        for (int rr = 0; rr < 4; ++rr) {
            const int r = quad * 4 + rr;
            float tot = rsumE[rw * 64 + r] + rsumE[rw * 64 + 16 + r]
                      + rsumE[rw * 64 + 32 + r] + rsumE[rw * 64 + 48 + r];
            float Mv = sM[rowbase + r];
            float n = fmaxf(tot, __expf(-Mv)) + 1e-6f;
            inv[rr] = 1.0f / n;
            ss[rr] = 0.f;
        }
        #pragma unroll
        for (int nn = 0; nn < 4; ++nn) {
            #pragma unroll
            for (int rr = 0; rr < 4; ++rr) {
                float hv = acc[nn][rr] * inv[rr];
                acc[nn][rr] = hv;
                ss[rr] = fmaf(hv, hv, ss[rr]);
            }
        }
        #pragma unroll
        for (int m = 1; m < 16; m <<= 1) {
            #pragma unroll
            for (int rr = 0; rr < 4; ++rr) ss[rr] += __shfl_xor(ss[rr], m);
        }
        if (col == 0) {
            #pragma unroll
            for (int rr = 0; rr < 4; ++rr)
                ssE[rw * 64 + cq * 16 + quad * 4 + rr] = ss[rr];
        }
        __syncthreads();
        #pragma unroll
        for (int rr = 0; rr < 4; ++rr) {
            const int r = quad * 4 + rr;
            float sst = ssE[rw * 64 + r] + ssE[rw * 64 + 16 + r]
                      + ssE[rw * 64 + 32 + r] + ssE[rw * 64 + 48 + r];
            float rstd = rsqrtf(sst * (1.0f / HD_) + 1e-6f);
            float* orow = out + ((size_t)(b * S_ + rowbase + r)) * E_ + h * HD_;
            #pragma unroll
            for (int nn = 0; nn < 4; ++nn) {
                const int c = cq * 64 + nn * 16 + col;
                orow[c] = acc[nn][rr] * rstd * (1.0f + rms_scale[c]);
            }
        }
        __syncthreads();   // epilogue done before next pass reuses rsumE/ssE/Ks/Vs
    }
}

extern "C" void kernel_launch(void* const* d_in, const int* in_sizes, int n_in,
                              void* d_out, int out_size, void* d_ws, size_t ws_size,
                              hipStream_t stream) {
    (void)in_sizes; (void)n_in; (void)out_size; (void)ws_size;
    const float* q   = (const float*)d_in[0];
    const float* k   = (const float*)d_in[1];
    const float* v   = (const float*)d_in[2];
    const float* igk = (const float*)d_in[3];
    const float* igb = (const float*)d_in[4];
    const float* fgk = (const float*)d_in[5];
    const float* fgb = (const float*)d_in[6];
    const float* rsc = (const float*)d_in[7];
    float* out = (float*)d_out;

    float* ws  = (float*)d_ws;
    float* ig  = ws;                          // BH*S each
    float* fg  = ws + (size_t)BH_ * S_;
    _Float16* Qh = (_Float16*)(ws + (size_t)2 * BH_ * S_);
    _Float16* Kh = Qh + (size_t)BH_ * S_ * HD_;
    _Float16* Vt = Kh + (size_t)BH_ * S_ * HD_;

    prep_kernel<<<B_ * S_ / 16, 1024, 0, stream>>>(q, k, v, igk, igb, fgk, fgb,
                                                   ig, fg, Qh, Kh, Vt);
    mlstm_kernel<<<BH_ * 32, 512, 0, stream>>>(Qh, Kh, Vt, ig, fg, rsc, out);
}